// Round 13
// baseline (124.833 us; speedup 1.0000x reference)
//
#include <hip/hip_runtime.h>
#include <hip/hip_bf16.h>

// GMM log-likelihood, N=65536, K=32, F=128.
// De-phased structure: 512-thr block (8 waves, 2/SIMD), 1 block/CU, grid 256.
// Wave (gh,nq) owns 64 g x 64 n (16 ds_read_b128 -> 32 MFMAs/comp, 1:2).
// LDS = 4-slab window (128 KB); ONE barrier per 2-comp batch: batch b reads
// window half A, stages half B (slabs 2b+2,2b+3). Between barriers waves
// free-run -> the two waves of a SIMD de-phase and their LDS/MFMA/VALU
// phases overlap (the per-comp barrier lockstep serialized all three pipes:
// 1800+2065+1230 ~= the measured 5590 cyc/comp wall of R10/R12).
// Pairwise combine DEFERRED to the batch tail: per-comp half-sums kept in 4
// regs, exchanged via parity-double-buffered xch after the batch barrier,
// then 2 LSE steps in the next batch's read shadow. v-trick mean fold.
// Register audit ~226/256: xf[2][8]=64, fr[8]=32, acc 64, xv 16, zc 16.

#define NPTS 65536
#define KC 32
#define FD 128
#define SLABB 32768  // 4 q * 8 s * 64 lanes * 16 B per component

typedef __attribute__((ext_vector_type(8))) short short8;
typedef __attribute__((ext_vector_type(8))) unsigned short ushort8;
typedef __attribute__((ext_vector_type(16))) float f32x16;

#define MFMA(A, B, C) __builtin_amdgcn_mfma_f32_32x32x16_bf16((A), (B), (C), 0, 0, 0)

static __device__ __forceinline__ unsigned short f2bf(float f) {
  unsigned int u = __float_as_uint(f);
  u += 0x7FFFu + ((u >> 16) & 1u);  // RNE
  return (unsigned short)(u >> 16);
}

static __device__ __forceinline__ void gll(const unsigned char* g, unsigned char* l) {
  __builtin_amdgcn_global_load_lds((const __attribute__((address_space(1))) void*)g,
                                   (__attribute__((address_space(3))) void*)l, 16, 0, 0);
}

// --- prep12: fused. smp[g] = mu_k @ P_k[:,g]; v[k][f] = P_k[f,:] @ smp;
//     ck3[k] = log w + logdet - 0.5*(F*log2pi + sum_g smp^2) ---
__global__ void prep12(const float* __restrict__ means, const float* __restrict__ P,
                       const float* __restrict__ w, float* __restrict__ v,
                       float* __restrict__ ck3) {
  int k = blockIdx.x, g = threadIdx.x;  // 32 x 128
  const float* Pk = P + k * FD * FD;
  float acc = 0.f;
  for (int f = 0; f < FD; ++f) acc = fmaf(means[k * FD + f], Pk[f * FD + g], acc);
  __shared__ float smp[FD], r1[FD], r2[FD];
  smp[g] = acc;
  r1[g] = logf(Pk[g * FD + g]);
  r2[g] = acc * acc;
  __syncthreads();
  const float* Pr = Pk + g * FD;
  float a2 = 0.f;
  for (int j = 0; j < FD; ++j) a2 = fmaf(Pr[j], smp[j], a2);
  v[k * FD + g] = a2;
  for (int off = 64; off; off >>= 1) {
    if (g < off) { r1[g] += r1[g + off]; r2[g] += r2[g + off]; }
    __syncthreads();
  }
  if (g == 0)
    ck3[k] = logf(w[k]) + r1[0] - 0.5f * ((float)FD * 1.8378770664093453f + r2[0]);
}

// --- prep3: xv mini-slab (8 KB): A'[row k][f] = v[k][f], frag-major ---
__global__ void prep3(const float* __restrict__ v, unsigned char* __restrict__ Ximg) {
  int id = blockIdx.x * 256 + threadIdx.x;  // 0..511 chunks
  int l = id & 63, s = id >> 6;
  int r = l & 31, f0 = 16 * s + 8 * (l >> 5);
  ushort8 o;
#pragma unroll
  for (int j = 0; j < 8; ++j) o[j] = f2bf(v[r * FD + f0 + j]);
  *(ushort8*)(Ximg + (size_t)id * 16) = o;
}

// --- prep4: frag-major bf16 A image. chunk id -> (k,q,s,lane). ---
__global__ void prep4(const float* __restrict__ P, unsigned char* __restrict__ Aimg) {
  int id = blockIdx.x * 256 + threadIdx.x;  // 0..65535
  int l = id & 63;
  int s = (id >> 6) & 7;
  int q = (id >> 9) & 3;
  int k = id >> 11;
  int g = q * 32 + (l & 31);
  int f0 = 16 * s + 8 * (l >> 5);
  ushort8 o;
#pragma unroll
  for (int j = 0; j < 8; ++j) o[j] = f2bf(P[k * 16384 + (f0 + j) * 128 + g]);
  *(ushort8*)(Aimg + (size_t)id * 16) = o;
}

// --- per-comp compute: 16 ds_reads, 32 MFMAs, squares, shfl -> half-sums ---
__device__ __forceinline__ void comp_half(const unsigned char* rb, int gh,
                                          const short8 (&xf)[2][8], const f32x16& zc,
                                          float& sown, float& soth) {
  short8 fr[8];
#pragma unroll
  for (int s = 0; s < 8; ++s) fr[s] = *(const short8*)(rb + s * 1024);
  __builtin_amdgcn_s_setprio(1);
  f32x16 a00 = MFMA(fr[0], xf[0][0], zc);
  f32x16 a01 = MFMA(fr[0], xf[1][0], zc);
#pragma unroll
  for (int s = 1; s < 8; ++s) {
    a00 = MFMA(fr[s], xf[0][s], a00);
    a01 = MFMA(fr[s], xf[1][s], a01);
  }
#pragma unroll
  for (int s = 0; s < 8; ++s) fr[s] = *(const short8*)(rb + 8192 + s * 1024);
  f32x16 a10 = MFMA(fr[0], xf[0][0], zc);
  f32x16 a11 = MFMA(fr[0], xf[1][0], zc);
#pragma unroll
  for (int s = 1; s < 8; ++s) {
    a10 = MFMA(fr[s], xf[0][s], a10);
    a11 = MFMA(fr[s], xf[1][s], a11);
  }
  __builtin_amdgcn_s_setprio(0);
  float q0a = 0.f, q0b = 0.f, q1a = 0.f, q1b = 0.f;
#pragma unroll
  for (int i = 0; i < 16; ++i) {
    q0a = fmaf(a00[i], a00[i], q0a);
    q0b = fmaf(a10[i], a10[i], q0b);
    q1a = fmaf(a01[i], a01[i], q1a);
    q1b = fmaf(a11[i], a11[i], q1b);
  }
  float q0 = q0a + q0b, q1 = q1a + q1b;
  q0 += __shfl_xor(q0, 32, 64);  // both halves hold full 64-g partials
  q1 += __shfl_xor(q1, 32, 64);
  sown = gh ? q1 : q0;  // n-tile this wave finalizes (t == gh)
  soth = gh ? q0 : q1;  // n-tile the partner (wid^1) finalizes
}

// --- main ---
__global__ __launch_bounds__(512, 2) void gmm_main(const float* __restrict__ x,
                                                   const unsigned char* __restrict__ Aimg,
                                                   const unsigned char* __restrict__ Ximg,
                                                   const float* __restrict__ ck3,
                                                   float* __restrict__ out) {
  __shared__ __align__(16) unsigned char abuf[4 * SLABB];  // 128 KB window
  __shared__ __align__(16) float xch[2][2][8][32];         // [parity][c][wave][ln]
  __shared__ float ck[KC];
  const int tid = threadIdx.x;
  const int wid = tid >> 6;   // 0..7
  const int lane = tid & 63;
  const int half = lane >> 5;
  const int ln = lane & 31;
  const int gh = wid & 1;     // g-half this wave owns (g-tiles gh*2, gh*2+1)
  const int nq = wid >> 1;    // n-quarter this wave owns (64 x-rows)
  const int nbase = blockIdx.x * 256;

  if (tid < KC) ck[tid] = ck3[tid];

  // prologue staging: slab0 -> slot0, slab1 -> slot1, Ximg -> slot2 (free)
  {
    const unsigned char* g0 = Aimg + wid * 4096 + lane * 16;
    unsigned char* l0 = abuf + wid * 4096;
#pragma unroll
    for (int i = 0; i < 4; ++i) gll(g0 + i * 1024, l0 + i * 1024);
    const unsigned char* g1 = Aimg + SLABB + wid * 4096 + lane * 16;
    unsigned char* l1 = abuf + SLABB + wid * 4096;
#pragma unroll
    for (int i = 0; i < 4; ++i) gll(g1 + i * 1024, l1 + i * 1024);
    gll(Ximg + wid * 1024 + lane * 16, abuf + 2 * SLABB + wid * 1024);
  }

  // B fragments: this wave's 64 x-rows (2 n-tiles), resident all kernel.
  // xf[t][s][j] = x[nbase + nq*64 + t*32 + ln][16s + 8*half + j]  (64 VGPR)
  short8 xf[2][8];
#pragma unroll
  for (int t = 0; t < 2; ++t) {
    const float* xr = x + (size_t)(nbase + nq * 64 + t * 32 + ln) * FD + 8 * half;
#pragma unroll
    for (int s = 0; s < 8; ++s) {
      const float4 a = *(const float4*)(xr + 16 * s);
      const float4 b = *(const float4*)(xr + 16 * s + 4);
      short8 f;
      f[0] = (short)f2bf(a.x); f[1] = (short)f2bf(a.y);
      f[2] = (short)f2bf(a.z); f[3] = (short)f2bf(a.w);
      f[4] = (short)f2bf(b.x); f[5] = (short)f2bf(b.y);
      f[6] = (short)f2bf(b.z); f[7] = (short)f2bf(b.w);
      xf[t][s] = f;
    }
  }

  f32x16 zc;  // persistent zero C-operand
#pragma unroll
  for (int i = 0; i < 16; ++i) zc[i] = 0.f;

  asm volatile("s_waitcnt vmcnt(0)" ::: "memory");
  __syncthreads();  // slab0, slab1, Ximg resident

  // xv[n,k] mini-GEMM for the n-tile this wave finalizes (t == gh):
  // row k = (i&3)+8*(i>>2)+4*half, col n = nbase + nq*64 + gh*32 + ln
  f32x16 xv;
  {
    const unsigned char* xb = abuf + 2 * SLABB + lane * 16;
    {
      const short8 fx = *(const short8*)xb;
      xv = MFMA(fx, xf[gh][0], zc);
    }
#pragma unroll
    for (int s = 1; s < 8; ++s) {
      const short8 fx = *(const short8*)(xb + s * 1024);
      xv = MFMA(fx, xf[gh][s], xv);
    }
  }
  __syncthreads();  // Ximg consumed -> slot2 reusable for slab 2 staging

  float m = -__builtin_inff(), ssum = 0.f;

  for (int b = 0; b < KC / 2; ++b) {
    const int k0 = 2 * b;
    const int rdb = (b & 1) ? 2 * SLABB : 0;  // window half to read
    const int stb = 2 * SLABB - rdb;          // window half to stage into
    const int bp = b & 1;
    // stage slabs k0+2, k0+3 (issued first; drained at batch end ~2 comps later)
    if (k0 + 2 < KC) {
      const unsigned char* gs = Aimg + (size_t)(k0 + 2) * SLABB + wid * 4096 + lane * 16;
      unsigned char* ls = abuf + stb + wid * 4096;
#pragma unroll
      for (int i = 0; i < 4; ++i) gll(gs + i * 1024, ls + i * 1024);
      const unsigned char* gs2 = gs + SLABB;
      unsigned char* ls2 = ls + SLABB;
#pragma unroll
      for (int i = 0; i < 4; ++i) gll(gs2 + i * 1024, ls2 + i * 1024);
    }
    // two comps, no intra-batch sync: waves free-run and de-phase
    float sownA, sothA, sownB, sothB;
    comp_half(abuf + rdb + gh * 16384 + lane * 16, gh, xf, zc, sownA, sothA);
    if (half == 0) xch[bp][0][wid ^ 1][ln] = sothA;
    comp_half(abuf + rdb + SLABB + gh * 16384 + lane * 16, gh, xf, zc, sownB, sothB);
    if (half == 0) xch[bp][1][wid ^ 1][ln] = sothB;
    asm volatile("s_waitcnt vmcnt(0)" ::: "memory");  // 8 gll from batch start
    __syncthreads();  // ONE barrier per 2 comps: publishes slabs + xch
    // batch tail: combine + LSE for k0, k0+1 (runs in next batch's read shadow)
#pragma unroll
    for (int c = 0; c < 2; ++c) {
      const int k = k0 + c;
      float sfull = (c ? sownB : sownA) + xch[bp][c][wid][ln];
      const int owner = (k >> 2) & 1;
      const int idx = (k & 3) | ((k >> 3) << 2);
      float tx = (half == owner) ? xv[idx] : 0.f;
      tx += __shfl_xor(tx, 32, 64);
      sfull = fmaf(-2.f, tx, sfull);
      float vv = ck[k] - 0.5f * sfull;
      float nm = fmaxf(m, vv);
      ssum = ssum * __expf(m - nm) + __expf(vv - nm);
      m = nm;
    }
  }

  if (half == 0) out[nbase + nq * 64 + gh * 32 + ln] = m + logf(ssum);
}

extern "C" void kernel_launch(void* const* d_in, const int* in_sizes, int n_in,
                              void* d_out, int out_size, void* d_ws, size_t ws_size,
                              hipStream_t stream) {
  const float* x = (const float*)d_in[0];
  const float* means = (const float*)d_in[1];
  const float* P = (const float*)d_in[2];
  const float* w = (const float*)d_in[3];
  float* out = (float*)d_out;

  unsigned char* ws = (unsigned char*)d_ws;
  unsigned char* Aimg = ws;                       // 1048576 B
  unsigned char* Ximg = ws + 1048576;             // 8192 B
  float* v = (float*)(ws + 1048576 + 8192);       // 16384 B
  float* ck3 = (float*)(ws + 1048576 + 24576);    // 128 B

  prep12<<<32, 128, 0, stream>>>(means, P, w, v, ck3);
  prep3<<<2, 256, 0, stream>>>(v, Ximg);
  prep4<<<256, 256, 0, stream>>>(P, Aimg);
  gmm_main<<<NPTS / 256, 512, 0, stream>>>(x, Aimg, Ximg, ck3, out);
}

// Round 14
// 85.833 us; speedup vs baseline: 1.4544x; 1.4544x over previous
//
#include <hip/hip_runtime.h>
#include <hip/hip_bf16.h>

// GMM log-likelihood, N=65536, K=32, F=128.
// 8-phase-discipline port (m201 template): 512-thr block (8 waves, 2/SIMD),
// grid 256 (1 block/CU). Wave (gh,nq) owns 64 g x 64 n: per comp 2 phases of
// {8 ds_read + stage/epilogue VALU -> raw s_barrier -> lgkmcnt(0) ->
//  setprio(1) 16-MFMA cluster setprio(0) -> raw s_barrier}.
// NO __syncthreads in the loop (it emits a vmcnt(0) drain -- the convoy that
// capped every prior design at ~37% MfmaUtil). Counted s_waitcnt vmcnt(4)
// once per comp; 3-slab LDS ring staged 2 comps ahead. Epilogue(k-1) split
// across the phases on lifetime-disjoint accumulators (squares of aLo(k-1)
// before aLo is overwritten, aHi likewise in phase B); LSE after last
// barrier. v-trick mean fold with xv in an LDS table (1 broadcast read/comp).
// Arch-reg audit ~126/128: xf[2][8]=64, fr[8]=32, temps ~30; acc 64 + zc 16
// in AGPR.

#define NPTS 65536
#define KC 32
#define FD 128
#define SLABB 32768  // 4 q * 8 s * 64 lanes * 16 B per component

typedef __attribute__((ext_vector_type(8))) short short8;
typedef __attribute__((ext_vector_type(8))) unsigned short ushort8;
typedef __attribute__((ext_vector_type(16))) float f32x16;

#define MFMA(A, B, C) __builtin_amdgcn_mfma_f32_32x32x16_bf16((A), (B), (C), 0, 0, 0)
#define SBAR() __builtin_amdgcn_s_barrier()
#define CFENCE() asm volatile("" ::: "memory")

static __device__ __forceinline__ unsigned short f2bf(float f) {
  unsigned int u = __float_as_uint(f);
  u += 0x7FFFu + ((u >> 16) & 1u);  // RNE
  return (unsigned short)(u >> 16);
}

static __device__ __forceinline__ void gll(const unsigned char* g, unsigned char* l) {
  __builtin_amdgcn_global_load_lds((const __attribute__((address_space(1))) void*)g,
                                   (__attribute__((address_space(3))) void*)l, 16, 0, 0);
}

// --- prep12: fused. smp[g] = mu_k @ P_k[:,g]; v[k][f] = P_k[f,:] @ smp;
//     ck3[k] = log w + logdet - 0.5*(F*log2pi + sum_g smp^2) ---
__global__ void prep12(const float* __restrict__ means, const float* __restrict__ P,
                       const float* __restrict__ w, float* __restrict__ v,
                       float* __restrict__ ck3) {
  int k = blockIdx.x, g = threadIdx.x;  // 32 x 128
  const float* Pk = P + k * FD * FD;
  float acc = 0.f;
  for (int f = 0; f < FD; ++f) acc = fmaf(means[k * FD + f], Pk[f * FD + g], acc);
  __shared__ float smp[FD], r1[FD], r2[FD];
  smp[g] = acc;
  r1[g] = logf(Pk[g * FD + g]);
  r2[g] = acc * acc;
  __syncthreads();
  const float* Pr = Pk + g * FD;
  float a2 = 0.f;
  for (int j = 0; j < FD; ++j) a2 = fmaf(Pr[j], smp[j], a2);
  v[k * FD + g] = a2;
  for (int off = 64; off; off >>= 1) {
    if (g < off) { r1[g] += r1[g + off]; r2[g] += r2[g + off]; }
    __syncthreads();
  }
  if (g == 0)
    ck3[k] = logf(w[k]) + r1[0] - 0.5f * ((float)FD * 1.8378770664093453f + r2[0]);
}

// --- prep3: xv mini-slab (8 KB): A'[row k][f] = v[k][f], frag-major ---
__global__ void prep3(const float* __restrict__ v, unsigned char* __restrict__ Ximg) {
  int id = blockIdx.x * 256 + threadIdx.x;  // 0..511 chunks
  int l = id & 63, s = id >> 6;
  int r = l & 31, f0 = 16 * s + 8 * (l >> 5);
  ushort8 o;
#pragma unroll
  for (int j = 0; j < 8; ++j) o[j] = f2bf(v[r * FD + f0 + j]);
  *(ushort8*)(Ximg + (size_t)id * 16) = o;
}

// --- prep4: frag-major bf16 A image. chunk id -> (k,q,s,lane). ---
__global__ void prep4(const float* __restrict__ P, unsigned char* __restrict__ Aimg) {
  int id = blockIdx.x * 256 + threadIdx.x;  // 0..65535
  int l = id & 63;
  int s = (id >> 6) & 7;
  int q = (id >> 9) & 3;
  int k = id >> 11;
  int g = q * 32 + (l & 31);
  int f0 = 16 * s + 8 * (l >> 5);
  ushort8 o;
#pragma unroll
  for (int j = 0; j < 8; ++j) o[j] = f2bf(P[k * 16384 + (f0 + j) * 128 + g]);
  *(ushort8*)(Aimg + (size_t)id * 16) = o;
}

// --- main ---
__global__ __launch_bounds__(512, 2) void gmm_main(const float* __restrict__ x,
                                                   const unsigned char* __restrict__ Aimg,
                                                   const unsigned char* __restrict__ Ximg,
                                                   const float* __restrict__ ck3,
                                                   float* __restrict__ out) {
  __shared__ __align__(16) unsigned char abuf[3 * SLABB];  // 96 KB ring
  __shared__ __align__(16) float xvt[8][KC][32];           // 32 KB xv table
  __shared__ __align__(16) float xch[2][8][32];            // parity-dbuf exchange
  __shared__ float ck[KC];
  const int tid = threadIdx.x;
  const int wid = tid >> 6;   // 0..7
  const int lane = tid & 63;
  const int half = lane >> 5;
  const int ln = lane & 31;
  const int gh = wid & 1;     // g-half this wave owns (g-tiles gh*2, gh*2+1)
  const int nq = wid >> 1;    // n-quarter this wave owns (64 x-rows)
  const int nbase = blockIdx.x * 256;

  if (tid < KC) ck[tid] = ck3[tid];

  // prologue staging: slab0 -> slot0, slab1 -> slot1, Ximg -> slot2
  {
    const unsigned char* g0 = Aimg + wid * 4096 + lane * 16;
    unsigned char* l0 = abuf + wid * 4096;
#pragma unroll
    for (int i = 0; i < 4; ++i) gll(g0 + i * 1024, l0 + i * 1024);
    const unsigned char* g1 = Aimg + SLABB + wid * 4096 + lane * 16;
    unsigned char* l1 = abuf + SLABB + wid * 4096;
#pragma unroll
    for (int i = 0; i < 4; ++i) gll(g1 + i * 1024, l1 + i * 1024);
    gll(Ximg + wid * 1024 + lane * 16, abuf + 2 * SLABB + wid * 1024);
  }

  // B fragments: this wave's 64 x-rows (2 n-tiles), resident all kernel.
  // xf[t][s][j] = x[nbase + nq*64 + t*32 + ln][16s + 8*half + j]  (64 VGPR)
  short8 xf[2][8];
#pragma unroll
  for (int t = 0; t < 2; ++t) {
    const float* xr = x + (size_t)(nbase + nq * 64 + t * 32 + ln) * FD + 8 * half;
#pragma unroll
    for (int s = 0; s < 8; ++s) {
      const float4 a = *(const float4*)(xr + 16 * s);
      const float4 b = *(const float4*)(xr + 16 * s + 4);
      short8 f;
      f[0] = (short)f2bf(a.x); f[1] = (short)f2bf(a.y);
      f[2] = (short)f2bf(a.z); f[3] = (short)f2bf(a.w);
      f[4] = (short)f2bf(b.x); f[5] = (short)f2bf(b.y);
      f[6] = (short)f2bf(b.z); f[7] = (short)f2bf(b.w);
      xf[t][s] = f;
    }
  }

  f32x16 zc;  // persistent zero C-operand
#pragma unroll
  for (int i = 0; i < 16; ++i) zc[i] = 0.f;

  asm volatile("s_waitcnt vmcnt(0)" ::: "memory");
  __syncthreads();  // prologue only: slab0, slab1, Ximg resident

  // xv mini-GEMM for the n-tile this wave finalizes (t == gh) -> LDS table.
  // row k = (i&3)+8*(i>>2)+4*half, col n = nbase + nq*64 + gh*32 + ln
  {
    const unsigned char* xb = abuf + 2 * SLABB + lane * 16;
    f32x16 xv;
    {
      const short8 fx = *(const short8*)xb;
      xv = MFMA(fx, xf[gh][0], zc);
    }
#pragma unroll
    for (int s = 1; s < 8; ++s) {
      const short8 fx = *(const short8*)(xb + s * 1024);
      xv = MFMA(fx, xf[gh][s], xv);
    }
#pragma unroll
    for (int i = 0; i < 16; ++i) {
      const int kk = (i & 3) + 8 * (i >> 2) + 4 * half;
      xvt[wid][kk][ln] = xv[i];
    }
  }
  __syncthreads();  // prologue only: xvt published; slot2 free for slab2

  float m = -__builtin_inff(), ssum = 0.f;
  f32x16 aLo0, aLo1, aHi0, aHi1;  // comp k's accs; k-1's values squared before overwrite
  int r0 = 0, r1 = SLABB, r2 = 2 * SLABB;

  for (int k = 0; k < KC; ++k) {
    const unsigned char* rb = abuf + r0 + gh * 16384 + lane * 16;
    // ---------- phase A ----------
    short8 fr[8];
#pragma unroll
    for (int s = 0; s < 8; ++s) fr[s] = *(const short8*)(rb + s * 1024);
    if (k + 2 < KC) {  // stage slab k+2 into ring slot r2 (4 gll per wave)
      const unsigned char* gs = Aimg + (size_t)(k + 2) * SLABB + wid * 4096 + lane * 16;
      unsigned char* ls = abuf + r2 + wid * 4096;
#pragma unroll
      for (int i = 0; i < 4; ++i) gll(gs + i * 1024, ls + i * 1024);
    }
    float q0 = 0.f, q1 = 0.f;
    if (k > 0) {  // squares of aLo(k-1) BEFORE this comp's MFMAs overwrite it
#pragma unroll
      for (int i = 0; i < 16; ++i) {
        q0 = fmaf(aLo0[i], aLo0[i], q0);
        q1 = fmaf(aLo1[i], aLo1[i], q1);
      }
    }
    CFENCE(); SBAR(); CFENCE();
    asm volatile("s_waitcnt lgkmcnt(0)" ::: "memory");
    __builtin_amdgcn_s_setprio(1);
    aLo0 = MFMA(fr[0], xf[0][0], zc);
    aLo1 = MFMA(fr[0], xf[1][0], zc);
#pragma unroll
    for (int s = 1; s < 8; ++s) {
      aLo0 = MFMA(fr[s], xf[0][s], aLo0);
      aLo1 = MFMA(fr[s], xf[1][s], aLo1);
    }
    __builtin_amdgcn_s_setprio(0);
    CFENCE(); SBAR(); CFENCE();
    // ---------- phase B ----------
#pragma unroll
    for (int s = 0; s < 8; ++s) fr[s] = *(const short8*)(rb + 8192 + s * 1024);
    float sown = 0.f, soth = 0.f;
    if (k > 0) {  // finish epilogue(k-1): aHi squares + shfl + xch write
#pragma unroll
      for (int i = 0; i < 16; ++i) {
        q0 = fmaf(aHi0[i], aHi0[i], q0);
        q1 = fmaf(aHi1[i], aHi1[i], q1);
      }
      q0 += __shfl_xor(q0, 32, 64);
      q1 += __shfl_xor(q1, 32, 64);
      sown = gh ? q1 : q0;
      soth = gh ? q0 : q1;
      if (half == 0) xch[(k - 1) & 1][wid ^ 1][ln] = soth;
    }
    // counted wait ONCE per comp: drain slab k+1's loads (one comp old, ~free),
    // leave this comp's 4 staging loads in flight across the barrier.
    if (k + 2 < KC) asm volatile("s_waitcnt vmcnt(4) lgkmcnt(0)" ::: "memory");
    else            asm volatile("s_waitcnt vmcnt(0) lgkmcnt(0)" ::: "memory");
    SBAR(); CFENCE();
    asm volatile("s_waitcnt lgkmcnt(0)" ::: "memory");
    __builtin_amdgcn_s_setprio(1);
    aHi0 = MFMA(fr[0], xf[0][0], zc);
    aHi1 = MFMA(fr[0], xf[1][0], zc);
#pragma unroll
    for (int s = 1; s < 8; ++s) {
      aHi0 = MFMA(fr[s], xf[0][s], aHi0);
      aHi1 = MFMA(fr[s], xf[1][s], aHi1);
    }
    __builtin_amdgcn_s_setprio(0);
    CFENCE(); SBAR(); CFENCE();
    if (k > 0) {  // LSE(k-1) in the shadow of next comp's phase A
      float sfull = sown + xch[(k - 1) & 1][wid][ln];
      sfull = fmaf(-2.f, xvt[wid][k - 1][ln], sfull);
      float vv = ck[k - 1] - 0.5f * sfull;
      float nm = fmaxf(m, vv);
      ssum = ssum * __expf(m - nm) + __expf(vv - nm);
      m = nm;
    }
    const int rt = r0; r0 = r1; r1 = r2; r2 = rt;  // rotate ring
  }

  // tail epilogue for comp 31
  {
    float q0 = 0.f, q1 = 0.f;
#pragma unroll
    for (int i = 0; i < 16; ++i) {
      q0 = fmaf(aLo0[i], aLo0[i], q0); q0 = fmaf(aHi0[i], aHi0[i], q0);
      q1 = fmaf(aLo1[i], aLo1[i], q1); q1 = fmaf(aHi1[i], aHi1[i], q1);
    }
    q0 += __shfl_xor(q0, 32, 64);
    q1 += __shfl_xor(q1, 32, 64);
    float sown = gh ? q1 : q0;
    float soth = gh ? q0 : q1;
    if (half == 0) xch[1][wid ^ 1][ln] = soth;
    __syncthreads();
    float sfull = sown + xch[1][wid][ln];
    sfull = fmaf(-2.f, xvt[wid][KC - 1][ln], sfull);
    float vv = ck[KC - 1] - 0.5f * sfull;
    float nm = fmaxf(m, vv);
    ssum = ssum * __expf(m - nm) + __expf(vv - nm);
    m = nm;
  }

  if (half == 0) out[nbase + nq * 64 + gh * 32 + ln] = m + logf(ssum);
}

extern "C" void kernel_launch(void* const* d_in, const int* in_sizes, int n_in,
                              void* d_out, int out_size, void* d_ws, size_t ws_size,
                              hipStream_t stream) {
  const float* x = (const float*)d_in[0];
  const float* means = (const float*)d_in[1];
  const float* P = (const float*)d_in[2];
  const float* w = (const float*)d_in[3];
  float* out = (float*)d_out;

  unsigned char* ws = (unsigned char*)d_ws;
  unsigned char* Aimg = ws;                       // 1048576 B
  unsigned char* Ximg = ws + 1048576;             // 8192 B
  float* v = (float*)(ws + 1048576 + 8192);       // 16384 B
  float* ck3 = (float*)(ws + 1048576 + 24576);    // 128 B

  prep12<<<32, 128, 0, stream>>>(means, P, w, v, ck3);
  prep3<<<2, 256, 0, stream>>>(v, Ximg);
  prep4<<<256, 256, 0, stream>>>(P, Aimg);
  gmm_main<<<NPTS / 256, 512, 0, stream>>>(x, Aimg, Ximg, ck3, out);
}